// Round 13
// baseline (567.282 us; speedup 1.0000x reference)
//
#include <hip/hip_runtime.h>
#include <math.h>

#define N    257     // state dim
#define AP   258     // doubles per A row (cols 0..256 = S, col 257 = rhs)
#define MM   128     // rotation pairs
#define LL   512     // seq length
#define BB   4       // batch
#define NB   32      // panel width
#define U12S 226     // U12 row stride

// ws byte layout (round-6/11 verified):
#define A_BYTE    0         // double[257*258] = 530448
#define W0_BYTE   530448    // float[257]  -> 531476
#define CXY_BYTE  531488    // float[4096] -> 547872
#define PW_BYTE   547904    // double[32*257] = 65792 -> 613696
#define U12_BYTE  613696    // double[32*226] = 57856 -> 671552
#define ST_BYTE   671552    // float[257*257] = 264196 -> 935748
// total ~936 KB (ws >= 1.31 MB)

// ---------------------------------------------------------------------------
// stage + scan in ONE dispatch (verified r9/r10/r11): blocks 0..129 stage
// A=[S|z0] fp64 + St=S^T fp32; block 130 does the prefix-sum scan.
// ---------------------------------------------------------------------------
__global__ __launch_bounds__(512) void stage_scan_kernel(const float* __restrict__ S,
                                                         const float* __restrict__ z0,
                                                         const float* __restrict__ x,
                                                         void* __restrict__ wsv) {
  const int tid = threadIdx.x;
  const int bid = blockIdx.x;

  if (bid < 130) {
    double* A  = (double*)((char*)wsv + A_BYTE);
    float*  St = (float*)((char*)wsv + ST_BYTE);
    const int idx = bid * 512 + tid;
    if (idx < N * N) {
      const int i = idx / N, j = idx - i * N;
      A[(size_t)i * AP + j] = (double)S[idx];
      St[idx] = S[j * N + i];          // St[d][i] = S[i][d]
    } else if (idx < N * N + N) {
      const int r = idx - N * N;
      A[(size_t)r * AP + N] = (double)z0[r];
    }
    return;
  }

  const int wave = tid >> 6, lane = tid & 63;
  const int b    = wave >> 1, comp = wave & 1;
  const float* xp = x + ((size_t)b * LL) * 2 + comp;
  double loc[8];
  double run = 0.0;
  #pragma unroll
  for (int e = 0; e < 8; ++e) {
    run += (double)xp[(lane * 8 + e) * 2];
    loc[e] = run;
  }
  double tot = run;
  #pragma unroll
  for (int off = 1; off < 64; off <<= 1) {
    const double o = __shfl_up(tot, off);
    if (lane >= off) tot += o;
  }
  const double excl = tot - run;
  float* cp = (float*)((char*)wsv + CXY_BYTE) + ((size_t)b * LL) * 2 + comp;
  #pragma unroll
  for (int e = 0; e < 8; ++e)
    cp[(lane * 8 + e) * 2] = (float)(excl + loc[e]);
}

// ---------------------------------------------------------------------------
// panel factor (round-13): HYBRID shfl-band + barrier-free triangular pass.
//
// r11 cost model (22us): 32 barriers + 32x31 LDS pivot broadcasts x 5 waves
// through one LDS pipe. This structure removes both:
//  phase 1: wave 0 holds band rows k0..k0+63 in registers and factors the
//           32 pivots via __shfl (pivot row passed in-register, 0 barriers);
//           publishes F11 (pivot rows) + pinv to LDS, below-band rows -> Pw.
//  ONE __syncthreads.
//  phase 2: threads 64..319 own the other 193 rows; each runs the unified
//           triangular Jordan recurrence (same math as r11, proven) against
//           F11s with NO barriers. U12 solve unchanged (r11 body), but its
//           column buffer REUSES r[] (liveness-disjoint) - round-0's 53us
//           came from 3 separate register arrays spilling (VGPR=68), and
//           round-12's regression from double2-cast LDS access (VGPR=72).
//           Only r[32] is declared here; all LDS traffic is scalar.
// VGPR check: expect >=90 (resident). 72 => spilled => revert.
// ---------------------------------------------------------------------------
__global__ __launch_bounds__(320, 1) void panel_factor_kernel(void* __restrict__ wsv,
                                                              int k0) {
  __shared__ double F11s[NB][NB + 1];    // pivot rows (L below diag, U above)
  __shared__ double pinv[NB];
  double* A    = (double*)((char*)wsv + A_BYTE);
  double* Pw   = (double*)((char*)wsv + PW_BYTE);
  double* U12w = (double*)((char*)wsv + U12_BYTE);
  const int tid = threadIdx.x;
  const int ct  = k0 + NB;
  const int tc2 = 258 - ct;              // trailing cols incl rhs

  // ---- row assignment ----
  int myrow;
  if (tid < 64) {
    myrow = k0 + tid;                            // band rows (32 pivots + 32)
  } else {
    const int rr = tid - 64;
    myrow = (rr < k0) ? rr : rr + 64;            // all other rows
  }
  const bool act = myrow < N;

  // ---- stage my row's panel slice into registers (coalesced-ish, L2) ----
  double r[NB];
  if (act) {
    const double* Ar = A + (size_t)myrow * AP + k0;   // 16B aligned
    #pragma unroll
    for (int c = 0; c < NB; c += 2) {
      const double2 v = *(const double2*)&Ar[c];
      r[c] = v.x; r[c + 1] = v.y;
    }
  }

  // ---- phase 1: wave 0 factors the band via shfl (no barriers) ----
  if (tid < 64) {
    #pragma unroll
    for (int j = 0; j < NB; ++j) {
      const double ujj = __shfl(r[j], j);        // pivot diag from lane j
      const double pj  = 1.0 / ujj;
      const double m   = r[j] * pj;
      #pragma unroll
      for (int j2 = j + 1; j2 < NB; ++j2) {
        const double uv = __shfl(r[j2], j);      // pivot row element
        if (tid > j && act) r[j2] -= m * uv;
      }
      if (tid > j && act) r[j] = m;
    }
    if (tid < NB) {
      // pivot rows: publish F11 + pinv, write band back to A (finish needs U)
      #pragma unroll
      for (int c = 0; c < NB; ++c) {
        F11s[tid][c] = r[c];
        A[(size_t)(k0 + tid) * AP + k0 + c] = r[c];
      }
      pinv[tid] = 1.0 / r[tid];
    } else if (act) {
      // below-band rows: factors -> Pw
      #pragma unroll
      for (int t = 0; t < NB; ++t)
        Pw[(size_t)t * N + myrow] = r[t];
    }
  }
  __syncthreads();                               // F11s + pinv ready

  // ---- phase 2: remaining 193 rows, barrier-free triangular pass ----
  if (tid >= 64 && act) {
    #pragma unroll
    for (int j = 0; j < NB; ++j) {
      const double f = r[j] * pinv[j];
      #pragma unroll
      for (int j2 = j + 1; j2 < NB; ++j2)
        r[j2] -= f * F11s[j][j2];                // scalar LDS broadcast
      r[j] = f;
    }
    #pragma unroll
    for (int t = 0; t < NB; ++t)
      Pw[(size_t)t * N + myrow] = r[t];
  }

  // ---- U12 forward solve: thread owns column tid; REUSES r[] as buffer ----
  if (tid < tc2) {
    #pragma unroll
    for (int jr = 0; jr < NB; ++jr)
      r[jr] = A[(size_t)(k0 + jr) * AP + ct + tid];   // coalesced across tid
    #pragma unroll
    for (int jr = 1; jr < NB; ++jr) {
      double vv = r[jr];
      #pragma unroll
      for (int t = 0; t < jr; ++t)
        vv -= F11s[jr][t] * r[t];                // F11 broadcast, r in regs
      r[jr] = vv;
    }
    #pragma unroll
    for (int jr = 0; jr < NB; ++jr) {
      U12w[jr * U12S + tid] = r[jr];
      A[(size_t)(k0 + jr) * AP + ct + tid] = r[jr];
    }
  }
}

// ---------------------------------------------------------------------------
// panel update (rank-32 Jordan GEMM), round-6/11 verified body (p = 0..6):
//   rows R = [0,k0) U [ct,N)  (225 rows; gr = rb<k0 ? rb : rb+32)
//   cols [ct, 258): A[gr][c] -= sum_t Pw[t][gr] * U12[t][c-ct]
// block tile = 32 rows x 64 cols; thread tile = 2x4.
// ---------------------------------------------------------------------------
__global__ __launch_bounds__(256) void panel_update_kernel(void* __restrict__ wsv,
                                                           int k0, int tc2) {
  __shared__ double Pl[NB][NB + 1];
  __shared__ __align__(16) double Ul[NB][66];
  double* A = (double*)((char*)wsv + A_BYTE);
  const double* Pw   = (const double*)((const char*)wsv + PW_BYTE);
  const double* U12w = (const double*)((const char*)wsv + U12_BYTE);
  const int tid = threadIdx.x;
  const int ct  = k0 + NB;
  const int rb0 = blockIdx.x * 32;
  const int c0  = blockIdx.y * 64;

  for (int i = tid; i < 32 * 32; i += 256) {
    const int t = i >> 5, rr = i & 31;
    const int rb = rb0 + rr;
    const int gr = (rb < k0) ? rb : rb + NB;
    Pl[t][rr] = (rb < 225) ? Pw[(size_t)t * N + gr] : 0.0;
  }
  for (int i = tid; i < 32 * 64; i += 256) {
    const int t = i >> 6, c = i & 63;
    Ul[t][c] = (c0 + c < tc2) ? U12w[t * U12S + c0 + c] : 0.0;
  }
  __syncthreads();

  const int tr  = tid >> 4;          // 0..15 -> rows tr*2 .. +1
  const int tcx = (tid & 15) * 4;    // cols tcx .. +3
  double acc[2][4];
  #pragma unroll
  for (int rr = 0; rr < 2; ++rr) {
    const int rb = rb0 + tr * 2 + rr;
    const int gr = (rb < k0) ? rb : rb + NB;
    #pragma unroll
    for (int c = 0; c < 4; ++c)
      acc[rr][c] = (rb < 225 && (c0 + tcx + c) < tc2)
                 ? A[(size_t)gr * AP + ct + c0 + tcx + c] : 0.0;
  }
  #pragma unroll
  for (int t = 0; t < NB; ++t) {
    const double p0 = Pl[t][tr * 2], p1 = Pl[t][tr * 2 + 1];
    const double2 u0 = *(const double2*)&Ul[t][tcx];
    const double2 u1 = *(const double2*)&Ul[t][tcx + 2];
    acc[0][0] -= p0 * u0.x; acc[0][1] -= p0 * u0.y;
    acc[0][2] -= p0 * u1.x; acc[0][3] -= p0 * u1.y;
    acc[1][0] -= p1 * u0.x; acc[1][1] -= p1 * u0.y;
    acc[1][2] -= p1 * u1.x; acc[1][3] -= p1 * u1.y;
  }
  #pragma unroll
  for (int rr = 0; rr < 2; ++rr) {
    const int rb = rb0 + tr * 2 + rr;
    const int gr = (rb < k0) ? rb : rb + NB;
    #pragma unroll
    for (int c = 0; c < 4; ++c)
      if (rb < 225 && (c0 + tcx + c) < tc2)
        A[(size_t)gr * AP + ct + c0 + tcx + c] = acc[rr][c];
  }
}

// ---------------------------------------------------------------------------
// last: update(p=7) (225 rows x 2 cols, rank-32) + finish back-substs
// (verified r11 body).
// ---------------------------------------------------------------------------
__global__ __launch_bounds__(256) void last_kernel(void* __restrict__ wsv) {
  __shared__ double xs[N];
  __shared__ double rr[256];
  double* A = (double*)((char*)wsv + A_BYTE);
  const double* Pw   = (const double*)((const char*)wsv + PW_BYTE);
  const double* U12w = (const double*)((const char*)wsv + U12_BYTE);
  float* w0f = (float*)((char*)wsv + W0_BYTE);
  const int tid = threadIdx.x;

  // update(7): rows [0,224) U {256}, cols {256, 257}
  for (int idx = tid; idx < 225 * 2; idx += 256) {
    const int rb = idx >> 1, c = idx & 1;
    const int gr = (rb < 224) ? rb : 256;
    double acc = A[(size_t)gr * AP + 256 + c];
    #pragma unroll
    for (int t = 0; t < NB; ++t)
      acc -= Pw[(size_t)t * N + gr] * U12w[t * U12S + c];
    A[(size_t)gr * AP + 256 + c] = acc;
  }
  __threadfence_block();
  __syncthreads();

  // finish (round-6 verified body)
  if (tid == 0) xs[256] = A[256 * AP + 257] / A[256 * AP + 256];
  __syncthreads();
  const double x256 = xs[256];
  rr[tid] = A[(size_t)tid * AP + 257] - A[(size_t)tid * AP + 256] * x256;
  __syncthreads();
  const int fk0 = tid & ~31;
  const int fs  = tid & 31;
  for (int j = 31; j >= 0; --j) {
    if (fs == j) xs[fk0 + j] = rr[fk0 + j] / A[(size_t)(fk0 + j) * AP + (fk0 + j)];
    __syncthreads();
    if (fs < j) rr[fk0 + fs] -= A[(size_t)(fk0 + fs) * AP + (fk0 + j)] * xs[fk0 + j];
    __syncthreads();
  }
  w0f[tid] = (float)xs[tid];
  if (tid == 0) w0f[256] = (float)xs[256];
}

// ---------------------------------------------------------------------------
// combine: out[(b,l), i] = sum_d St[d, i] * W[(b,l), d]   (round-4 verified)
// ---------------------------------------------------------------------------
#define NL 8
__global__ __launch_bounds__(320) void combine_kernel(const float* __restrict__ S,
                                                      const float* __restrict__ om,
                                                      const void* __restrict__ wsv,
                                                      float* __restrict__ out) {
  const int tid = threadIdx.x;
  const int b  = blockIdx.y;
  const int l0 = blockIdx.x * NL;
  const float* w0  = (const float*)((const char*)wsv + W0_BYTE);
  const float* cxy = (const float*)((const char*)wsv + CXY_BYTE);
  const float* St  = (const float*)((const char*)wsv + ST_BYTE);
  __shared__ __align__(16) float Wl[N][NL];
  __shared__ float omsh[2 * MM];
  __shared__ float cxs[NL], cys[NL];

  for (int idx = tid; idx < 2 * MM; idx += 320) omsh[idx] = om[idx];
  if (tid < NL) {
    cxs[tid] = cxy[((size_t)(b * LL) + l0 + tid) * 2];
    cys[tid] = cxy[((size_t)(b * LL) + l0 + tid) * 2 + 1];
  }
  __syncthreads();

  for (int idx = tid; idx < NL * N; idx += 320) {
    const int d = idx >> 3;
    const int r = idx & 7;
    float v;
    if (d == 0) {
      v = w0[0];
    } else {
      const int m = (d - 1) >> 1;
      const int pq = 2 * m + 1;
      const float t = cxs[r] * omsh[2 * m] + cys[r] * omsh[2 * m + 1];
      float s, c;
      sincosf(t, &s, &c);
      const float a0 = w0[pq], a1 = w0[pq + 1];
      v = (d & 1) ? (c * a0 - s * a1) : (s * a0 + c * a1);
    }
    Wl[d][r] = v;
  }
  __syncthreads();

  const int i = tid;
  if (i < N) {
    float acc[NL];
    #pragma unroll
    for (int r = 0; r < NL; ++r) acc[r] = 0.0f;
    #pragma unroll 8
    for (int d = 0; d < N; ++d) {
      const float stv = St[(size_t)d * N + i];
      const float4 wa = *(const float4*)&Wl[d][0];
      const float4 wb = *(const float4*)&Wl[d][4];
      acc[0] += stv * wa.x; acc[1] += stv * wa.y;
      acc[2] += stv * wa.z; acc[3] += stv * wa.w;
      acc[4] += stv * wb.x; acc[5] += stv * wb.y;
      acc[6] += stv * wb.z; acc[7] += stv * wb.w;
    }
    const size_t base = (size_t)(b * LL + l0) * N + i;
    #pragma unroll
    for (int r = 0; r < NL; ++r) out[base + (size_t)r * N] = acc[r];
    if (l0 + NL == LL) {
      out[(size_t)BB * LL * N + (size_t)b * N + i] = acc[NL - 1];
    }
  }
}

extern "C" void kernel_launch(void* const* d_in, const int* in_sizes, int n_in,
                              void* d_out, int out_size, void* d_ws, size_t ws_size,
                              hipStream_t stream) {
  const float* x  = (const float*)d_in[0];   // (B, L, 2)
  const float* z0 = (const float*)d_in[1];   // (D,)
  const float* om = (const float*)d_in[2];   // (M, 2)
  const float* S  = (const float*)d_in[3];   // (D, D)
  float* out = (float*)d_out;                // outputs (B,L,D) then z_final (B,D)

  hipLaunchKernelGGL(stage_scan_kernel, dim3(131), dim3(512), 0, stream, S, z0, x, d_ws);
  for (int p = 0; p < 8; ++p) {
    const int k0  = p * NB;
    const int tc2 = 258 - (k0 + NB);
    hipLaunchKernelGGL(panel_factor_kernel, dim3(1), dim3(320), 0, stream, d_ws, k0);
    if (p < 7)
      hipLaunchKernelGGL(panel_update_kernel, dim3(8, (tc2 + 63) / 64), dim3(256),
                         0, stream, d_ws, k0, tc2);
  }
  hipLaunchKernelGGL(last_kernel, dim3(1), dim3(256), 0, stream, d_ws);
  hipLaunchKernelGGL(combine_kernel, dim3(LL / NL, BB), dim3(320), 0, stream, S, om, d_ws, out);
}

// Round 14
// 300.490 us; speedup vs baseline: 1.8879x; 1.8879x over previous
//
#include <hip/hip_runtime.h>
#include <math.h>

#define N    257     // state dim
#define AP   258     // floats per A row (cols 0..256 = S, col 257 = rhs)
#define MM   128     // rotation pairs
#define LL   512     // seq length
#define BB   4       // batch
#define NB   32      // panel width
#define U12S 226     // U12 row stride

// ws byte layout (round-14: LU pipeline in fp32; reference itself is fp32):
#define A_BYTE    0         // float[257*258] = 265224
#define W0_BYTE   265224    // float[257]  -> 266252
#define CXY_BYTE  266256    // float[4096] -> 282640
#define PW_BYTE   282640    // float[32*257] = 32896 -> 315536
#define U12_BYTE  315536    // float[32*226] = 28928 -> 344464
#define ST_BYTE   344464    // float[257*257] = 264196 -> 608660
// total ~609 KB (ws >= 1.31 MB)

// ---------------------------------------------------------------------------
// stage + scan in ONE dispatch (verified r9-r11 structure; A now fp32):
// blocks 0..129 stage A=[S|z0] + St=S^T; block 130 does the prefix-sum scan.
// ---------------------------------------------------------------------------
__global__ __launch_bounds__(512) void stage_scan_kernel(const float* __restrict__ S,
                                                         const float* __restrict__ z0,
                                                         const float* __restrict__ x,
                                                         void* __restrict__ wsv) {
  const int tid = threadIdx.x;
  const int bid = blockIdx.x;

  if (bid < 130) {
    float* A  = (float*)((char*)wsv + A_BYTE);
    float* St = (float*)((char*)wsv + ST_BYTE);
    const int idx = bid * 512 + tid;
    if (idx < N * N) {
      const int i = idx / N, j = idx - i * N;
      A[(size_t)i * AP + j] = S[idx];
      St[idx] = S[j * N + i];          // St[d][i] = S[i][d]
    } else if (idx < N * N + N) {
      const int r = idx - N * N;
      A[(size_t)r * AP + N] = z0[r];
    }
    return;
  }

  const int wave = tid >> 6, lane = tid & 63;
  const int b    = wave >> 1, comp = wave & 1;
  const float* xp = x + ((size_t)b * LL) * 2 + comp;
  double loc[8];
  double run = 0.0;
  #pragma unroll
  for (int e = 0; e < 8; ++e) {
    run += (double)xp[(lane * 8 + e) * 2];
    loc[e] = run;
  }
  double tot = run;
  #pragma unroll
  for (int off = 1; off < 64; off <<= 1) {
    const double o = __shfl_up(tot, off);
    if (lane >= off) tot += o;
  }
  const double excl = tot - run;
  float* cp = (float*)((char*)wsv + CXY_BYTE) + ((size_t)b * LL) * 2 + comp;
  #pragma unroll
  for (int e = 0; e < 8; ++e)
    cp[(lane * 8 + e) * 2] = (float)(excl + loc[e]);
}

// ---------------------------------------------------------------------------
// panel factor: the r11-VERIFIED register-resident Jordan body, fp32.
// Structure untouched (single uniform role context, scalar LDS traffic,
// ONE declared register array) - the only spill-free form found (r0/r8/r12/
// r13 all spilled via other structures). fp32 halves the dependent-chain
// latency and removes the VGPR cliff (r[32] = 32 VGPRs).
// ---------------------------------------------------------------------------
__global__ __launch_bounds__(320, 1) void panel_factor_kernel(void* __restrict__ wsv,
                                                              int k0) {
  __shared__ float piv[2][NB];           // double-buffered pivot row trailing
  __shared__ float pinvs[2];
  __shared__ float F11s[NB][NB + 1];     // L11\U11 block (for U12 solve)
  float* A    = (float*)((char*)wsv + A_BYTE);
  float* Pw   = (float*)((char*)wsv + PW_BYTE);
  float* U12w = (float*)((char*)wsv + U12_BYTE);
  const int tid = threadIdx.x;
  const int ct  = k0 + NB;
  const int tc2 = 258 - ct;              // trailing cols incl rhs

  // ---- stage my row's panel slice into registers (L2-resident A) ----
  float r[NB];
  if (tid < N) {
    const float* Ar = A + (size_t)tid * AP + k0;   // 8B-aligned (k0 even)
    #pragma unroll
    for (int c = 0; c < NB; c += 2) {
      const float2 v = *(const float2*)&Ar[c];
      r[c] = v.x; r[c + 1] = v.y;
    }
  }

  // ---- pre-step: pivot row k0 publishes itself ----
  if (tid == k0) {
    #pragma unroll
    for (int c = 0; c < NB; ++c) piv[0][c] = r[c];
    pinvs[0] = 1.0f / r[0];
  }
  __syncthreads();

  // ---- 32 Jordan steps, rows in registers, pivot row via LDS broadcast ----
  #pragma unroll
  for (int j = 0; j < NB; ++j) {
    const int pr = k0 + j;
    const int bsel = j & 1;
    if (tid < N && (tid < k0 || tid > pr)) {   // frozen: pivot rows k0..pr
      const float f = r[j] * pinvs[bsel];
      #pragma unroll
      for (int j2 = j + 1; j2 < NB; ++j2)
        r[j2] -= f * piv[bsel][j2];
      r[j] = f;
      if (j + 1 < NB && tid == pr + 1) {       // publish next pivot row
        #pragma unroll
        for (int c = 0; c < NB; ++c)
          if (c > j) piv[bsel ^ 1][c] = r[c];
        pinvs[bsel ^ 1] = 1.0f / r[j + 1];
      }
    }
    __syncthreads();
  }

  // ---- publish: pivot band -> F11s + A; other rows -> Pw ----
  if (tid < N) {
    if (tid >= k0 && tid < ct) {
      const int fr = tid - k0;
      #pragma unroll
      for (int c = 0; c < NB; ++c) {
        F11s[fr][c] = r[c];
        A[(size_t)tid * AP + k0 + c] = r[c];   // U11/L11 for finish kernel
      }
    } else {
      #pragma unroll
      for (int t = 0; t < NB; ++t)
        Pw[(size_t)t * N + tid] = r[t];
    }
  }
  __syncthreads();                             // F11s ready

  // ---- U12 forward solve: thread owns column, u[] in registers ----
  if (tid < tc2) {
    float u[NB];
    #pragma unroll
    for (int jr = 0; jr < NB; ++jr)
      u[jr] = A[(size_t)(k0 + jr) * AP + ct + tid];   // coalesced across tid
    #pragma unroll
    for (int jr = 1; jr < NB; ++jr) {
      float vv = u[jr];
      #pragma unroll
      for (int t = 0; t < jr; ++t)
        vv -= F11s[jr][t] * u[t];              // F11 broadcast, u in regs
      u[jr] = vv;
    }
    #pragma unroll
    for (int jr = 0; jr < NB; ++jr) {
      U12w[jr * U12S + tid] = u[jr];
      A[(size_t)(k0 + jr) * AP + ct + tid] = u[jr];
    }
  }
}

// ---------------------------------------------------------------------------
// panel update (rank-32 Jordan GEMM), r6/r11-verified body in fp32 (p=0..6):
//   rows R = [0,k0) U [ct,N)  (225 rows; gr = rb<k0 ? rb : rb+32)
//   cols [ct, 258): A[gr][c] -= sum_t Pw[t][gr] * U12[t][c-ct]
// block tile = 32 rows x 64 cols; thread tile = 2x4.
// ---------------------------------------------------------------------------
__global__ __launch_bounds__(256) void panel_update_kernel(void* __restrict__ wsv,
                                                           int k0, int tc2) {
  __shared__ float Pl[NB][NB + 1];
  __shared__ __align__(16) float Ul[NB][66];
  float* A = (float*)((char*)wsv + A_BYTE);
  const float* Pw   = (const float*)((const char*)wsv + PW_BYTE);
  const float* U12w = (const float*)((const char*)wsv + U12_BYTE);
  const int tid = threadIdx.x;
  const int ct  = k0 + NB;
  const int rb0 = blockIdx.x * 32;
  const int c0  = blockIdx.y * 64;

  for (int i = tid; i < 32 * 32; i += 256) {
    const int t = i >> 5, rr = i & 31;
    const int rb = rb0 + rr;
    const int gr = (rb < k0) ? rb : rb + NB;
    Pl[t][rr] = (rb < 225) ? Pw[(size_t)t * N + gr] : 0.0f;
  }
  for (int i = tid; i < 32 * 64; i += 256) {
    const int t = i >> 6, c = i & 63;
    Ul[t][c] = (c0 + c < tc2) ? U12w[t * U12S + c0 + c] : 0.0f;
  }
  __syncthreads();

  const int tr  = tid >> 4;          // 0..15 -> rows tr*2 .. +1
  const int tcx = (tid & 15) * 4;    // cols tcx .. +3
  float acc[2][4];
  #pragma unroll
  for (int rr = 0; rr < 2; ++rr) {
    const int rb = rb0 + tr * 2 + rr;
    const int gr = (rb < k0) ? rb : rb + NB;
    #pragma unroll
    for (int c = 0; c < 4; ++c)
      acc[rr][c] = (rb < 225 && (c0 + tcx + c) < tc2)
                 ? A[(size_t)gr * AP + ct + c0 + tcx + c] : 0.0f;
  }
  #pragma unroll
  for (int t = 0; t < NB; ++t) {
    const float p0 = Pl[t][tr * 2], p1 = Pl[t][tr * 2 + 1];
    const float2 u0 = *(const float2*)&Ul[t][tcx];
    const float2 u1 = *(const float2*)&Ul[t][tcx + 2];
    acc[0][0] -= p0 * u0.x; acc[0][1] -= p0 * u0.y;
    acc[0][2] -= p0 * u1.x; acc[0][3] -= p0 * u1.y;
    acc[1][0] -= p1 * u0.x; acc[1][1] -= p1 * u0.y;
    acc[1][2] -= p1 * u1.x; acc[1][3] -= p1 * u1.y;
  }
  #pragma unroll
  for (int rr = 0; rr < 2; ++rr) {
    const int rb = rb0 + tr * 2 + rr;
    const int gr = (rb < k0) ? rb : rb + NB;
    #pragma unroll
    for (int c = 0; c < 4; ++c)
      if (rb < 225 && (c0 + tcx + c) < tc2)
        A[(size_t)gr * AP + ct + c0 + tcx + c] = acc[rr][c];
  }
}

// ---------------------------------------------------------------------------
// last: update(p=7) (225 rows x 2 cols, rank-32) + finish back-substs
// (r11-verified body, fp32).
// ---------------------------------------------------------------------------
__global__ __launch_bounds__(256) void last_kernel(void* __restrict__ wsv) {
  __shared__ float xs[N];
  __shared__ float rr[256];
  float* A = (float*)((char*)wsv + A_BYTE);
  const float* Pw   = (const float*)((const char*)wsv + PW_BYTE);
  const float* U12w = (const float*)((const char*)wsv + U12_BYTE);
  float* w0f = (float*)((char*)wsv + W0_BYTE);
  const int tid = threadIdx.x;

  // update(7): rows [0,224) U {256}, cols {256, 257}
  for (int idx = tid; idx < 225 * 2; idx += 256) {
    const int rb = idx >> 1, c = idx & 1;
    const int gr = (rb < 224) ? rb : 256;
    float acc = A[(size_t)gr * AP + 256 + c];
    #pragma unroll
    for (int t = 0; t < NB; ++t)
      acc -= Pw[(size_t)t * N + gr] * U12w[t * U12S + c];
    A[(size_t)gr * AP + 256 + c] = acc;
  }
  __threadfence_block();
  __syncthreads();

  // finish (r6-verified body, fp32)
  if (tid == 0) xs[256] = A[256 * AP + 257] / A[256 * AP + 256];
  __syncthreads();
  const float x256 = xs[256];
  rr[tid] = A[(size_t)tid * AP + 257] - A[(size_t)tid * AP + 256] * x256;
  __syncthreads();
  const int fk0 = tid & ~31;
  const int fs  = tid & 31;
  for (int j = 31; j >= 0; --j) {
    if (fs == j) xs[fk0 + j] = rr[fk0 + j] / A[(size_t)(fk0 + j) * AP + (fk0 + j)];
    __syncthreads();
    if (fs < j) rr[fk0 + fs] -= A[(size_t)(fk0 + fs) * AP + (fk0 + j)] * xs[fk0 + j];
    __syncthreads();
  }
  w0f[tid] = xs[tid];
  if (tid == 0) w0f[256] = xs[256];
}

// ---------------------------------------------------------------------------
// combine: out[(b,l), i] = sum_d St[d, i] * W[(b,l), d]   (round-4 verified)
// ---------------------------------------------------------------------------
#define NL 8
__global__ __launch_bounds__(320) void combine_kernel(const float* __restrict__ S,
                                                      const float* __restrict__ om,
                                                      const void* __restrict__ wsv,
                                                      float* __restrict__ out) {
  const int tid = threadIdx.x;
  const int b  = blockIdx.y;
  const int l0 = blockIdx.x * NL;
  const float* w0  = (const float*)((const char*)wsv + W0_BYTE);
  const float* cxy = (const float*)((const char*)wsv + CXY_BYTE);
  const float* St  = (const float*)((const char*)wsv + ST_BYTE);
  __shared__ __align__(16) float Wl[N][NL];
  __shared__ float omsh[2 * MM];
  __shared__ float cxs[NL], cys[NL];

  for (int idx = tid; idx < 2 * MM; idx += 320) omsh[idx] = om[idx];
  if (tid < NL) {
    cxs[tid] = cxy[((size_t)(b * LL) + l0 + tid) * 2];
    cys[tid] = cxy[((size_t)(b * LL) + l0 + tid) * 2 + 1];
  }
  __syncthreads();

  for (int idx = tid; idx < NL * N; idx += 320) {
    const int d = idx >> 3;
    const int r = idx & 7;
    float v;
    if (d == 0) {
      v = w0[0];
    } else {
      const int m = (d - 1) >> 1;
      const int pq = 2 * m + 1;
      const float t = cxs[r] * omsh[2 * m] + cys[r] * omsh[2 * m + 1];
      float s, c;
      sincosf(t, &s, &c);
      const float a0 = w0[pq], a1 = w0[pq + 1];
      v = (d & 1) ? (c * a0 - s * a1) : (s * a0 + c * a1);
    }
    Wl[d][r] = v;
  }
  __syncthreads();

  const int i = tid;
  if (i < N) {
    float acc[NL];
    #pragma unroll
    for (int r = 0; r < NL; ++r) acc[r] = 0.0f;
    #pragma unroll 8
    for (int d = 0; d < N; ++d) {
      const float stv = St[(size_t)d * N + i];
      const float4 wa = *(const float4*)&Wl[d][0];
      const float4 wb = *(const float4*)&Wl[d][4];
      acc[0] += stv * wa.x; acc[1] += stv * wa.y;
      acc[2] += stv * wa.z; acc[3] += stv * wa.w;
      acc[4] += stv * wb.x; acc[5] += stv * wb.y;
      acc[6] += stv * wb.z; acc[7] += stv * wb.w;
    }
    const size_t base = (size_t)(b * LL + l0) * N + i;
    #pragma unroll
    for (int r = 0; r < NL; ++r) out[base + (size_t)r * N] = acc[r];
    if (l0 + NL == LL) {
      out[(size_t)BB * LL * N + (size_t)b * N + i] = acc[NL - 1];
    }
  }
}

extern "C" void kernel_launch(void* const* d_in, const int* in_sizes, int n_in,
                              void* d_out, int out_size, void* d_ws, size_t ws_size,
                              hipStream_t stream) {
  const float* x  = (const float*)d_in[0];   // (B, L, 2)
  const float* z0 = (const float*)d_in[1];   // (D,)
  const float* om = (const float*)d_in[2];   // (M, 2)
  const float* S  = (const float*)d_in[3];   // (D, D)
  float* out = (float*)d_out;                // outputs (B,L,D) then z_final (B,D)

  hipLaunchKernelGGL(stage_scan_kernel, dim3(131), dim3(512), 0, stream, S, z0, x, d_ws);
  for (int p = 0; p < 8; ++p) {
    const int k0  = p * NB;
    const int tc2 = 258 - (k0 + NB);
    hipLaunchKernelGGL(panel_factor_kernel, dim3(1), dim3(320), 0, stream, d_ws, k0);
    if (p < 7)
      hipLaunchKernelGGL(panel_update_kernel, dim3(8, (tc2 + 63) / 64), dim3(256),
                         0, stream, d_ws, k0, tc2);
  }
  hipLaunchKernelGGL(last_kernel, dim3(1), dim3(256), 0, stream, d_ws);
  hipLaunchKernelGGL(combine_kernel, dim3(LL / NL, BB), dim3(320), 0, stream, S, om, d_ws, out);
}

// Round 16
// 296.460 us; speedup vs baseline: 1.9135x; 1.0136x over previous
//
#include <hip/hip_runtime.h>
#include <math.h>

#define N    257     // state dim
#define AP   258     // floats per A row (cols 0..256 = S, col 257 = rhs)
#define MM   128     // rotation pairs
#define LL   512     // seq length
#define BB   4       // batch
#define NB   32      // panel width
#define U12S 226     // U12 row stride

// ws byte layout (round-14 verified, fp32 LU):
#define A_BYTE    0         // float[257*258] = 265224
#define W0_BYTE   265224    // float[257]  -> 266252
#define CXY_BYTE  266256    // float[4096] -> 282640
#define PW_BYTE   282640    // float[32*257] = 32896 -> 315536
#define U12_BYTE  315536    // float[32*226] = 28928 -> 344464
#define ST_BYTE   344464    // float[257*257] = 264196 -> 608660
// total ~609 KB (ws >= 1.31 MB)

// ---------------------------------------------------------------------------
// stage + scan in ONE dispatch (r14 verified).
// ---------------------------------------------------------------------------
__global__ __launch_bounds__(512) void stage_scan_kernel(const float* __restrict__ S,
                                                         const float* __restrict__ z0,
                                                         const float* __restrict__ x,
                                                         void* __restrict__ wsv) {
  const int tid = threadIdx.x;
  const int bid = blockIdx.x;

  if (bid < 130) {
    float* A  = (float*)((char*)wsv + A_BYTE);
    float* St = (float*)((char*)wsv + ST_BYTE);
    const int idx = bid * 512 + tid;
    if (idx < N * N) {
      const int i = idx / N, j = idx - i * N;
      A[(size_t)i * AP + j] = S[idx];
      St[idx] = S[j * N + i];          // St[d][i] = S[i][d]
    } else if (idx < N * N + N) {
      const int r = idx - N * N;
      A[(size_t)r * AP + N] = z0[r];
    }
    return;
  }

  const int wave = tid >> 6, lane = tid & 63;
  const int b    = wave >> 1, comp = wave & 1;
  const float* xp = x + ((size_t)b * LL) * 2 + comp;
  double loc[8];
  double run = 0.0;
  #pragma unroll
  for (int e = 0; e < 8; ++e) {
    run += (double)xp[(lane * 8 + e) * 2];
    loc[e] = run;
  }
  double tot = run;
  #pragma unroll
  for (int off = 1; off < 64; off <<= 1) {
    const double o = __shfl_up(tot, off);
    if (lane >= off) tot += o;
  }
  const double excl = tot - run;
  float* cp = (float*)((char*)wsv + CXY_BYTE) + ((size_t)b * LL) * 2 + comp;
  #pragma unroll
  for (int e = 0; e < 8; ++e)
    cp[(lane * 8 + e) * 2] = (float)(excl + loc[e]);
}

// ---------------------------------------------------------------------------
// panel factor (round-16): r14 fp32 Jordan body; float4 applied to LOADS
// ONLY, operation order bit-identical to r14.
// r15 lesson: r14's absmax margin is razor-thin (1.625 vs 1.64, deterministic
// inputs). r15's grouped quad-sum in the U12 solve reassociated the fma chain
// -> absmax 6.69, FAIL. Here:
//  - Jordan loop: float4 piv reads, per-element update (bit-identical ops).
//  - U12 solve: float4 F11s reads, SEQUENTIAL vv -= fv.c * u[..] chain in
//    r14's exact order (each contracts to the same fma sequence).
// Check: absmax must be exactly 1.625; anything else => reassociation =>
// revert to r14. Spill discipline (r12): vectors only as read temps.
// ---------------------------------------------------------------------------
__global__ __launch_bounds__(320, 1) void panel_factor_kernel(void* __restrict__ wsv,
                                                              int k0) {
  __shared__ __align__(16) float piv[2][NB];       // 128B rows, 16B aligned
  __shared__ float pinvs[2];
  __shared__ __align__(16) float F11s[NB][NB + 4]; // 144B rows, 16B aligned
  float* A    = (float*)((char*)wsv + A_BYTE);
  float* Pw   = (float*)((char*)wsv + PW_BYTE);
  float* U12w = (float*)((char*)wsv + U12_BYTE);
  const int tid = threadIdx.x;
  const int ct  = k0 + NB;
  const int tc2 = 258 - ct;              // trailing cols incl rhs

  // ---- stage my row's panel slice into registers (L2-resident A) ----
  float r[NB];
  if (tid < N) {
    const float* Ar = A + (size_t)tid * AP + k0;
    #pragma unroll
    for (int c = 0; c < NB; c += 2) {
      const float2 v = *(const float2*)&Ar[c];
      r[c] = v.x; r[c + 1] = v.y;
    }
  }

  // ---- pre-step: pivot row k0 publishes itself (scalar stores) ----
  if (tid == k0) {
    #pragma unroll
    for (int c = 0; c < NB; ++c) piv[0][c] = r[c];
    pinvs[0] = 1.0f / r[0];
  }
  __syncthreads();

  // ---- 32 Jordan steps; pivot row via FLOAT4 LDS broadcast,
  //      per-element updates (bit-identical to r14) ----
  #pragma unroll
  for (int j = 0; j < NB; ++j) {
    const int pr = k0 + j;
    const int bsel = j & 1;
    if (tid < N && (tid < k0 || tid > pr)) {   // frozen: pivot rows k0..pr
      const float f = r[j] * pinvs[bsel];
      #pragma unroll
      for (int q = 0; q < NB / 4; ++q) {
        if (4 * q + 3 > j) {                   // quad has a live column
          const float4 pv = *(const float4*)&piv[bsel][4 * q];
          if (4 * q     > j) r[4 * q]     -= f * pv.x;   // compile-time guards
          if (4 * q + 1 > j) r[4 * q + 1] -= f * pv.y;
          if (4 * q + 2 > j) r[4 * q + 2] -= f * pv.z;
          r[4 * q + 3] -= f * pv.w;            // 4q+3 > j by outer guard
        }
      }
      r[j] = f;
      if (j + 1 < NB && tid == pr + 1) {       // publish next pivot row (scalar)
        #pragma unroll
        for (int c = 0; c < NB; ++c)
          if (c > j) piv[bsel ^ 1][c] = r[c];
        pinvs[bsel ^ 1] = 1.0f / r[j + 1];
      }
    }
    __syncthreads();
  }

  // ---- publish: pivot band -> F11s + A; other rows -> Pw (scalar) ----
  if (tid < N) {
    if (tid >= k0 && tid < ct) {
      const int fr = tid - k0;
      #pragma unroll
      for (int c = 0; c < NB; ++c) {
        F11s[fr][c] = r[c];
        A[(size_t)tid * AP + k0 + c] = r[c];   // U11/L11 for finish kernel
      }
    } else {
      #pragma unroll
      for (int t = 0; t < NB; ++t)
        Pw[(size_t)t * N + tid] = r[t];
    }
  }
  __syncthreads();                             // F11s ready

  // ---- U12 forward solve: float4 F11s reads, SEQUENTIAL fma chain
  //      (r14's exact operation order -> bit-identical) ----
  if (tid < tc2) {
    float u[NB];
    #pragma unroll
    for (int jr = 0; jr < NB; ++jr)
      u[jr] = A[(size_t)(k0 + jr) * AP + ct + tid];   // coalesced across tid
    #pragma unroll
    for (int jr = 1; jr < NB; ++jr) {
      float vv = u[jr];
      #pragma unroll
      for (int q = 0; q < jr / 4; ++q) {
        const float4 fv = *(const float4*)&F11s[jr][4 * q];
        vv -= fv.x * u[4 * q];                 // sequential, same order as r14
        vv -= fv.y * u[4 * q + 1];
        vv -= fv.z * u[4 * q + 2];
        vv -= fv.w * u[4 * q + 3];
      }
      #pragma unroll
      for (int t = (jr / 4) * 4; t < jr; ++t)
        vv -= F11s[jr][t] * u[t];              // remainder, scalar
      u[jr] = vv;
    }
    #pragma unroll
    for (int jr = 0; jr < NB; ++jr) {
      U12w[jr * U12S + tid] = u[jr];
      A[(size_t)(k0 + jr) * AP + ct + tid] = u[jr];
    }
  }
}

// ---------------------------------------------------------------------------
// panel update (rank-32 Jordan GEMM), r14-verified fp32 body (p = 0..6).
// ---------------------------------------------------------------------------
__global__ __launch_bounds__(256) void panel_update_kernel(void* __restrict__ wsv,
                                                           int k0, int tc2) {
  __shared__ float Pl[NB][NB + 1];
  __shared__ __align__(16) float Ul[NB][66];
  float* A = (float*)((char*)wsv + A_BYTE);
  const float* Pw   = (const float*)((const char*)wsv + PW_BYTE);
  const float* U12w = (const float*)((const char*)wsv + U12_BYTE);
  const int tid = threadIdx.x;
  const int ct  = k0 + NB;
  const int rb0 = blockIdx.x * 32;
  const int c0  = blockIdx.y * 64;

  for (int i = tid; i < 32 * 32; i += 256) {
    const int t = i >> 5, rr = i & 31;
    const int rb = rb0 + rr;
    const int gr = (rb < k0) ? rb : rb + NB;
    Pl[t][rr] = (rb < 225) ? Pw[(size_t)t * N + gr] : 0.0f;
  }
  for (int i = tid; i < 32 * 64; i += 256) {
    const int t = i >> 6, c = i & 63;
    Ul[t][c] = (c0 + c < tc2) ? U12w[t * U12S + c0 + c] : 0.0f;
  }
  __syncthreads();

  const int tr  = tid >> 4;          // 0..15 -> rows tr*2 .. +1
  const int tcx = (tid & 15) * 4;    // cols tcx .. +3
  float acc[2][4];
  #pragma unroll
  for (int rr = 0; rr < 2; ++rr) {
    const int rb = rb0 + tr * 2 + rr;
    const int gr = (rb < k0) ? rb : rb + NB;
    #pragma unroll
    for (int c = 0; c < 4; ++c)
      acc[rr][c] = (rb < 225 && (c0 + tcx + c) < tc2)
                 ? A[(size_t)gr * AP + ct + c0 + tcx + c] : 0.0f;
  }
  #pragma unroll
  for (int t = 0; t < NB; ++t) {
    const float p0 = Pl[t][tr * 2], p1 = Pl[t][tr * 2 + 1];
    const float2 u0 = *(const float2*)&Ul[t][tcx];
    const float2 u1 = *(const float2*)&Ul[t][tcx + 2];
    acc[0][0] -= p0 * u0.x; acc[0][1] -= p0 * u0.y;
    acc[0][2] -= p0 * u1.x; acc[0][3] -= p0 * u1.y;
    acc[1][0] -= p1 * u0.x; acc[1][1] -= p1 * u0.y;
    acc[1][2] -= p1 * u1.x; acc[1][3] -= p1 * u1.y;
  }
  #pragma unroll
  for (int rr = 0; rr < 2; ++rr) {
    const int rb = rb0 + tr * 2 + rr;
    const int gr = (rb < k0) ? rb : rb + NB;
    #pragma unroll
    for (int c = 0; c < 4; ++c)
      if (rb < 225 && (c0 + tcx + c) < tc2)
        A[(size_t)gr * AP + ct + c0 + tcx + c] = acc[rr][c];
  }
}

// ---------------------------------------------------------------------------
// last: update(p=7) (225 rows x 2 cols, rank-32) + finish back-substs
// (r14-verified fp32 body).
// ---------------------------------------------------------------------------
__global__ __launch_bounds__(256) void last_kernel(void* __restrict__ wsv) {
  __shared__ float xs[N];
  __shared__ float rr[256];
  float* A = (float*)((char*)wsv + A_BYTE);
  const float* Pw   = (const float*)((const char*)wsv + PW_BYTE);
  const float* U12w = (const float*)((const char*)wsv + U12_BYTE);
  float* w0f = (float*)((char*)wsv + W0_BYTE);
  const int tid = threadIdx.x;

  // update(7): rows [0,224) U {256}, cols {256, 257}
  for (int idx = tid; idx < 225 * 2; idx += 256) {
    const int rb = idx >> 1, c = idx & 1;
    const int gr = (rb < 224) ? rb : 256;
    float acc = A[(size_t)gr * AP + 256 + c];
    #pragma unroll
    for (int t = 0; t < NB; ++t)
      acc -= Pw[(size_t)t * N + gr] * U12w[t * U12S + c];
    A[(size_t)gr * AP + 256 + c] = acc;
  }
  __threadfence_block();
  __syncthreads();

  // finish (r6-verified body, fp32)
  if (tid == 0) xs[256] = A[256 * AP + 257] / A[256 * AP + 256];
  __syncthreads();
  const float x256 = xs[256];
  rr[tid] = A[(size_t)tid * AP + 257] - A[(size_t)tid * AP + 256] * x256;
  __syncthreads();
  const int fk0 = tid & ~31;
  const int fs  = tid & 31;
  for (int j = 31; j >= 0; --j) {
    if (fs == j) xs[fk0 + j] = rr[fk0 + j] / A[(size_t)(fk0 + j) * AP + (fk0 + j)];
    __syncthreads();
    if (fs < j) rr[fk0 + fs] -= A[(size_t)(fk0 + fs) * AP + (fk0 + j)] * xs[fk0 + j];
    __syncthreads();
  }
  w0f[tid] = xs[tid];
  if (tid == 0) w0f[256] = xs[256];
}

// ---------------------------------------------------------------------------
// combine: out[(b,l), i] = sum_d St[d, i] * W[(b,l), d]   (round-4 verified)
// ---------------------------------------------------------------------------
#define NL 8
__global__ __launch_bounds__(320) void combine_kernel(const float* __restrict__ S,
                                                      const float* __restrict__ om,
                                                      const void* __restrict__ wsv,
                                                      float* __restrict__ out) {
  const int tid = threadIdx.x;
  const int b  = blockIdx.y;
  const int l0 = blockIdx.x * NL;
  const float* w0  = (const float*)((const char*)wsv + W0_BYTE);
  const float* cxy = (const float*)((const char*)wsv + CXY_BYTE);
  const float* St  = (const float*)((const char*)wsv + ST_BYTE);
  __shared__ __align__(16) float Wl[N][NL];
  __shared__ float omsh[2 * MM];
  __shared__ float cxs[NL], cys[NL];

  for (int idx = tid; idx < 2 * MM; idx += 320) omsh[idx] = om[idx];
  if (tid < NL) {
    cxs[tid] = cxy[((size_t)(b * LL) + l0 + tid) * 2];
    cys[tid] = cxy[((size_t)(b * LL) + l0 + tid) * 2 + 1];
  }
  __syncthreads();

  for (int idx = tid; idx < NL * N; idx += 320) {
    const int d = idx >> 3;
    const int r = idx & 7;
    float v;
    if (d == 0) {
      v = w0[0];
    } else {
      const int m = (d - 1) >> 1;
      const int pq = 2 * m + 1;
      const float t = cxs[r] * omsh[2 * m] + cys[r] * omsh[2 * m + 1];
      float s, c;
      sincosf(t, &s, &c);
      const float a0 = w0[pq], a1 = w0[pq + 1];
      v = (d & 1) ? (c * a0 - s * a1) : (s * a0 + c * a1);
    }
    Wl[d][r] = v;
  }
  __syncthreads();

  const int i = tid;
  if (i < N) {
    float acc[NL];
    #pragma unroll
    for (int r = 0; r < NL; ++r) acc[r] = 0.0f;
    #pragma unroll 8
    for (int d = 0; d < N; ++d) {
      const float stv = St[(size_t)d * N + i];
      const float4 wa = *(const float4*)&Wl[d][0];
      const float4 wb = *(const float4*)&Wl[d][4];
      acc[0] += stv * wa.x; acc[1] += stv * wa.y;
      acc[2] += stv * wa.z; acc[3] += stv * wa.w;
      acc[4] += stv * wb.x; acc[5] += stv * wb.y;
      acc[6] += stv * wb.z; acc[7] += stv * wb.w;
    }
    const size_t base = (size_t)(b * LL + l0) * N + i;
    #pragma unroll
    for (int r = 0; r < NL; ++r) out[base + (size_t)r * N] = acc[r];
    if (l0 + NL == LL) {
      out[(size_t)BB * LL * N + (size_t)b * N + i] = acc[NL - 1];
    }
  }
}

extern "C" void kernel_launch(void* const* d_in, const int* in_sizes, int n_in,
                              void* d_out, int out_size, void* d_ws, size_t ws_size,
                              hipStream_t stream) {
  const float* x  = (const float*)d_in[0];   // (B, L, 2)
  const float* z0 = (const float*)d_in[1];   // (D,)
  const float* om = (const float*)d_in[2];   // (M, 2)
  const float* S  = (const float*)d_in[3];   // (D, D)
  float* out = (float*)d_out;                // outputs (B,L,D) then z_final (B,D)

  hipLaunchKernelGGL(stage_scan_kernel, dim3(131), dim3(512), 0, stream, S, z0, x, d_ws);
  for (int p = 0; p < 8; ++p) {
    const int k0  = p * NB;
    const int tc2 = 258 - (k0 + NB);
    hipLaunchKernelGGL(panel_factor_kernel, dim3(1), dim3(320), 0, stream, d_ws, k0);
    if (p < 7)
      hipLaunchKernelGGL(panel_update_kernel, dim3(8, (tc2 + 63) / 64), dim3(256),
                         0, stream, d_ws, k0, tc2);
  }
  hipLaunchKernelGGL(last_kernel, dim3(1), dim3(256), 0, stream, d_ws);
  hipLaunchKernelGGL(combine_kernel, dim3(LL / NL, BB), dim3(320), 0, stream, S, om, d_ws, out);
}